// Round 3
// baseline (2141.522 us; speedup 1.0000x reference)
//
#include <hip/hip_runtime.h>
#include <math.h>

#define SL 1024
#define NW 256

typedef _Float16 half8 __attribute__((ext_vector_type(8)));
typedef _Float16 half2t __attribute__((ext_vector_type(2)));
typedef float f32x4 __attribute__((ext_vector_type(4)));

__device__ __forceinline__ float rcp_f(float v) { return __builtin_amdgcn_rcpf(v); }

// mfma_f32_16x16x32_f16 layouts (guide-verified family):
//   A (16x32): lane row m = lane&15, k = (lane>>4)*8 + e (8 contig)
//   B (32x16): lane col n = lane&15, k = (lane>>4)*8 + e
//   D (16x16): lane col n = lane&15, row m = (lane>>4)*4 + reg
// Only batch rows 0,1 of A are nonzero -> lanes c>=2 feed A=0 from registers,
// and only g==0 lanes' acc regs 0,1 are meaningful.
__global__ __launch_bounds__(512, 2) void gru_mfma_kernel(
    const float* __restrict__ x, const float* __restrict__ w_ih,
    const float* __restrict__ w_hh, const float* __restrict__ b_ih,
    const float* __restrict__ b_hh, const float* __restrict__ fc_w,
    const float* __restrict__ fc_b, float* __restrict__ out)
{
    const int tid  = threadIdx.x;
    const int w    = tid >> 6;     // wave 0..7
    const int lane = tid & 63;
    const int c    = lane & 15;    // unit-in-tile / batch row for A
    const int g    = lane >> 4;    // k-group 0..3
    const int row0 = blockIdx.x * 2;

    __shared__ float    x_lds[2][1026];                   // m values; idx0 = 0.5 (t=-1)
    __shared__ __align__(16) _Float16 h_lds[2][2][264];   // dbuf, 2 batch rows only
    __shared__ float    dpart[SL][8][2];                  // per-step per-wave head partials
    __shared__ float    wsum[8][2];

    for (int i = tid; i < 2 * SL; i += 512) {
        int b = i >> 10, j = i & (SL - 1);
        x_lds[b][1 + j] = (x[(size_t)(row0 + b) * SL + j] + 1.0f) * 0.5f;
    }
    if (tid < 2) x_lds[tid][0] = 0.5f;
    for (int i = tid; i < 2 * 2 * 264; i += 512)
        ((_Float16*)h_lds)[i] = (_Float16)0.0f;

    // persistent B fragments: 6 unit-tiles x 8 k-tiles (f0,1=r f2,3=z f4,5=n)
    half8 B[6][8];
    #pragma unroll
    for (int f = 0; f < 6; ++f) {
        const int tile = (f >> 1) * 16 + 2 * w + (f & 1);
        const int u = tile * 16 + c;
        #pragma unroll
        for (int kt = 0; kt < 8; ++kt) {
            const float* p = w_hh + (size_t)u * NW + kt * 32 + g * 8;
            float4 lo = *(const float4*)p;
            float4 hi = *(const float4*)(p + 4);
            half8 hb;
            hb[0] = (_Float16)lo.x; hb[1] = (_Float16)lo.y;
            hb[2] = (_Float16)lo.z; hb[3] = (_Float16)lo.w;
            hb[4] = (_Float16)hi.x; hb[5] = (_Float16)hi.y;
            hb[6] = (_Float16)hi.z; hb[7] = (_Float16)hi.w;
            B[f][kt] = hb;
        }
    }

    // per-lane gate constants for units u0 = 32w + c, u1 = u0 + 16
    half2t pkr[2], pkz[2], pkn[2];
    float bhn[2], wd[2];
    #pragma unroll
    for (int p = 0; p < 2; ++p) {
        const int u = 32 * w + c + (p ? 16 : 0);
        float w0, w1, cm;
        w0 = w_ih[2 * u]; w1 = w_ih[2 * u + 1];
        cm = w1 + b_ih[u] + b_hh[u];
        pkr[p][0] = (_Float16)cm; pkr[p][1] = (_Float16)(w0 - w1);
        w0 = w_ih[2 * (NW + u)]; w1 = w_ih[2 * (NW + u) + 1];
        cm = w1 + b_ih[NW + u] + b_hh[NW + u];
        pkz[p][0] = (_Float16)cm; pkz[p][1] = (_Float16)(w0 - w1);
        w0 = w_ih[2 * (2 * NW + u)]; w1 = w_ih[2 * (2 * NW + u) + 1];
        cm = w1 + b_ih[2 * NW + u];
        pkn[p][0] = (_Float16)cm; pkn[p][1] = (_Float16)(w0 - w1);
        bhn[p] = b_hh[2 * NW + u];
        wd[p]  = fc_w[u] - fc_w[NW + u];
    }
    const float bd = fc_b[0] - fc_b[1];

    float h[2][2] = {{0.f, 0.f}, {0.f, 0.f}};
    const half8 zero8 = (half8)(_Float16)0.0f;

    __syncthreads();

    #pragma unroll 1
    for (int t = 0; t < SL; ++t) {
        const int cur = t & 1, nxt = cur ^ 1;
        const float m0 = x_lds[0][t];
        const float m1 = x_lds[1][t];

        f32x4 acc[6];
        #pragma unroll
        for (int f = 0; f < 6; ++f) { f32x4 z = {0.f, 0.f, 0.f, 0.f}; acc[f] = z; }

        #pragma unroll
        for (int kt = 0; kt < 8; ++kt) {
            half8 A = (c < 2) ? *(const half8*)&h_lds[cur][c][kt * 32 + g * 8] : zero8;
            #pragma unroll
            for (int f = 0; f < 6; ++f)
                acc[f] = __builtin_amdgcn_mfma_f32_16x16x32_f16(A, B[f][kt], acc[f], 0, 0, 0);
        }

        float hn[2][2];
        #pragma unroll
        for (int p = 0; p < 2; ++p) {
            const float cmr = (float)pkr[p][0], cdr = (float)pkr[p][1];
            const float cmz = (float)pkz[p][0], cdz = (float)pkz[p][1];
            const float cmn = (float)pkn[p][0], cdn = (float)pkn[p][1];
            #pragma unroll
            for (int r = 0; r < 2; ++r) {
                const float m  = r ? m1 : m0;
                const float vr = acc[p][r] + fmaf(m, cdr, cmr);
                const float rr = rcp_f(1.f + __expf(-vr));
                const float vz = acc[2 + p][r] + fmaf(m, cdz, cmz);
                const float zz = rcp_f(1.f + __expf(-vz));
                const float un = fmaf(rr, acc[4 + p][r] + bhn[p], fmaf(m, cdn, cmn));
                const float ng = fmaf(-2.f, rcp_f(1.f + __expf(2.f * un)), 1.f);
                const float v  = fmaf(zz, h[p][r] - ng, ng);
                hn[p][r] = v; h[p][r] = v;
            }
        }

        if (g == 0) {
            h_lds[nxt][0][32 * w + c]      = (_Float16)hn[0][0];
            h_lds[nxt][0][32 * w + 16 + c] = (_Float16)hn[1][0];
            h_lds[nxt][1][32 * w + c]      = (_Float16)hn[0][1];
            h_lds[nxt][1][32 * w + 16 + c] = (_Float16)hn[1][1];
        }
        __syncthreads();

        // deferred output-head partial (overlaps next step's ds_read + MFMA;
        // consumed only after the post-loop barrier)
        float v0 = fmaf(hn[0][0], wd[0], hn[1][0] * wd[1]);
        float v1 = fmaf(hn[0][1], wd[0], hn[1][1] * wd[1]);
        v0 += __shfl_xor(v0, 1); v0 += __shfl_xor(v0, 2);
        v0 += __shfl_xor(v0, 4); v0 += __shfl_xor(v0, 8);
        v1 += __shfl_xor(v1, 1); v1 += __shfl_xor(v1, 2);
        v1 += __shfl_xor(v1, 4); v1 += __shfl_xor(v1, 8);
        if (lane == 0) { dpart[t][w][0] = v0; dpart[t][w][1] = v1; }
    }

    __syncthreads();

    // post-loop: softplus over all steps, then block reduction
    float lpp0 = 0.f, lpp1 = 0.f;
    #pragma unroll 1
    for (int t = tid; t < SL; t += 512) {
        float d0 = bd, d1 = bd;
        #pragma unroll
        for (int q = 0; q < 8; ++q) { d0 += dpart[t][q][0]; d1 += dpart[t][q][1]; }
        const float u0 = (x_lds[0][t + 1] > 0.5f) ? -d0 : d0;
        const float u1 = (x_lds[1][t + 1] > 0.5f) ? -d1 : d1;
        lpp0 -= fmaxf(u0, 0.f) + __logf(1.f + __expf(-fabsf(u0)));
        lpp1 -= fmaxf(u1, 0.f) + __logf(1.f + __expf(-fabsf(u1)));
    }
    #pragma unroll
    for (int s = 1; s < 64; s <<= 1) {
        lpp0 += __shfl_xor(lpp0, s);
        lpp1 += __shfl_xor(lpp1, s);
    }
    if (lane == 0) { wsum[w][0] = lpp0; wsum[w][1] = lpp1; }
    __syncthreads();
    if (tid < 2) {
        float s = 0.f;
        #pragma unroll
        for (int q = 0; q < 8; ++q) s += wsum[q][tid];
        out[row0 + tid] = s;
    }
}

extern "C" void kernel_launch(void* const* d_in, const int* in_sizes, int n_in,
                              void* d_out, int out_size, void* d_ws, size_t ws_size,
                              hipStream_t stream) {
    const float* x    = (const float*)d_in[0];
    const float* w_ih = (const float*)d_in[1];
    const float* w_hh = (const float*)d_in[2];
    const float* b_ih = (const float*)d_in[3];
    const float* b_hh = (const float*)d_in[4];
    const float* fc_w = (const float*)d_in[5];
    const float* fc_b = (const float*)d_in[6];
    gru_mfma_kernel<<<256, 512, 0, stream>>>(
        x, w_ih, w_hh, b_ih, b_hh, fc_w, fc_b, (float*)d_out);
}

// Round 5
// 2046.531 us; speedup vs baseline: 1.0464x; 1.0464x over previous
//
#include <hip/hip_runtime.h>
#include <math.h>

#define SL 1024
#define NW 256

typedef _Float16 half8 __attribute__((ext_vector_type(8)));
typedef _Float16 half2t __attribute__((ext_vector_type(2)));
typedef float f32x4 __attribute__((ext_vector_type(4)));

__device__ __forceinline__ float rcp_f(float v) { return __builtin_amdgcn_rcpf(v); }

// mfma_f32_16x16x32_f16 layouts:
//   A (16x32): lane row m = lane&15, k = (lane>>4)*8 + e (8 contig)
//   B (32x16): lane col n = lane&15, k = (lane>>4)*8 + e
//   D (16x16): lane col n = lane&15, row m = (lane>>4)*4 + reg
// Broadcast-A: every lane reads h row (c&1) -> A rows 2..15 duplicate rows 0/1;
// D rows 2..15 are garbage and never consumed. h_lds row stride 288 halfs
// (576 B = 144 dw = 16 banks) -> row0/row1 chunks hit disjoint bank halves.
__global__ __launch_bounds__(512, 2) void gru_mfma_kernel(
    const float* __restrict__ x, const float* __restrict__ w_ih,
    const float* __restrict__ w_hh, const float* __restrict__ b_ih,
    const float* __restrict__ b_hh, const float* __restrict__ fc_w,
    const float* __restrict__ fc_b, float* __restrict__ out)
{
    const int tid  = threadIdx.x;
    const int w    = tid >> 6;     // wave 0..7
    const int lane = tid & 63;
    const int c    = lane & 15;    // unit-in-tile (B cols) / A row id
    const int g    = lane >> 4;    // k-group 0..3
    const int row0 = blockIdx.x * 2;

    __shared__ float    x_lds[2][1026];                   // m values; idx0 = 0.5 (t=-1)
    __shared__ __align__(16) _Float16 h_lds[2][2][288];   // dbuf, 2 rows, stride 288
    __shared__ float    dpart[SL][4];                     // per-step head halves (w6: 0,1  w7: 2,3)
    __shared__ float    wsum[8][2];

    for (int i = tid; i < 2 * SL; i += 512) {
        int b = i >> 10, j = i & (SL - 1);
        x_lds[b][1 + j] = (x[(size_t)(row0 + b) * SL + j] + 1.0f) * 0.5f;
    }
    if (tid < 2) x_lds[tid][0] = 0.5f;
    for (int i = tid; i < 2 * 2 * 288; i += 512)
        ((_Float16*)h_lds)[i] = (_Float16)0.0f;

    // persistent B fragments (6 unit-tiles x 8 k-tiles; f0,1=r f2,3=z f4,5=n)
    half8 Bf[6][8];
    #pragma unroll
    for (int f = 0; f < 6; ++f) {
        const int tile = (f >> 1) * 16 + 2 * w + (f & 1);
        const int u = tile * 16 + c;
        #pragma unroll
        for (int kt = 0; kt < 8; ++kt) {
            const float* p = w_hh + (size_t)u * NW + kt * 32 + g * 8;
            float4 lo = *(const float4*)p;
            float4 hi = *(const float4*)(p + 4);
            half8 hb;
            hb[0] = (_Float16)lo.x; hb[1] = (_Float16)lo.y;
            hb[2] = (_Float16)lo.z; hb[3] = (_Float16)lo.w;
            hb[4] = (_Float16)hi.x; hb[5] = (_Float16)hi.y;
            hb[6] = (_Float16)hi.z; hb[7] = (_Float16)hi.w;
            Bf[f][kt] = hb;
        }
    }

    // head fragments: B7 col0 = wd slice; wave6 covers kt 0..3, wave7 kt 4..7
    half8 B7f[4];
    #pragma unroll
    for (int j = 0; j < 4; ++j) B7f[j] = (half8)(_Float16)0.0f;
    if (w >= 6 && c == 0) {
        const int ktb = (w == 7) ? 4 : 0;
        #pragma unroll
        for (int j = 0; j < 4; ++j)
            #pragma unroll
            for (int e = 0; e < 8; ++e) {
                const int k = (ktb + j) * 32 + g * 8 + e;
                B7f[j][e] = (_Float16)(fc_w[k] - fc_w[NW + k]);
            }
    }

    // per-lane gate constants for units u0 = 32w + c, u1 = u0 + 16
    half2t pkr[2], pkz[2], pkn[2];
    float bhn[2];
    #pragma unroll
    for (int p = 0; p < 2; ++p) {
        const int u = 32 * w + c + (p ? 16 : 0);
        float w0, w1, cm;
        w0 = w_ih[2 * u]; w1 = w_ih[2 * u + 1];
        cm = w1 + b_ih[u] + b_hh[u];
        pkr[p][0] = (_Float16)cm; pkr[p][1] = (_Float16)(w0 - w1);
        w0 = w_ih[2 * (NW + u)]; w1 = w_ih[2 * (NW + u) + 1];
        cm = w1 + b_ih[NW + u] + b_hh[NW + u];
        pkz[p][0] = (_Float16)cm; pkz[p][1] = (_Float16)(w0 - w1);
        w0 = w_ih[2 * (2 * NW + u)]; w1 = w_ih[2 * (2 * NW + u) + 1];
        cm = w1 + b_ih[2 * NW + u];
        pkn[p][0] = (_Float16)cm; pkn[p][1] = (_Float16)(w0 - w1);
        bhn[p] = b_hh[2 * NW + u];
    }
    const float bd = fc_b[0] - fc_b[1];

    float h[2][2] = {{0.f, 0.f}, {0.f, 0.f}};

    __syncthreads();

    #pragma unroll 1
    for (int t = 0; t < SL; ++t) {
        const int cur = t & 1, nxt = cur ^ 1;
        const float m0 = x_lds[0][t];
        const float m1 = x_lds[1][t];

        f32x4 acc[6];
        #pragma unroll
        for (int f = 0; f < 6; ++f) { f32x4 z = {0.f, 0.f, 0.f, 0.f}; acc[f] = z; }
        f32x4 acc6 = {0.f, 0.f, 0.f, 0.f};

        #pragma unroll
        for (int kt = 0; kt < 8; ++kt) {
            half8 A = *(const half8*)&h_lds[cur][c & 1][kt * 32 + g * 8];
            #pragma unroll
            for (int f = 0; f < 6; ++f)
                acc[f] = __builtin_amdgcn_mfma_f32_16x16x32_f16(A, Bf[f][kt], acc[f], 0, 0, 0);
            // head uses h_t -> contributes to d_{t-1} (store shifted below)
            if (w == 6 && kt < 4)
                acc6 = __builtin_amdgcn_mfma_f32_16x16x32_f16(A, B7f[kt], acc6, 0, 0, 0);
            if (w == 7 && kt >= 4)
                acc6 = __builtin_amdgcn_mfma_f32_16x16x32_f16(A, B7f[kt - 4], acc6, 0, 0, 0);
        }
        if (w >= 6 && t != 0 && lane == 0) {
            dpart[t - 1][(w - 6) * 2]     = acc6[0];
            dpart[t - 1][(w - 6) * 2 + 1] = acc6[1];
        }

        float hn[2][2];
        #pragma unroll
        for (int p = 0; p < 2; ++p) {
            const float cmr = (float)pkr[p][0], cdr = (float)pkr[p][1];
            const float cmz = (float)pkz[p][0], cdz = (float)pkz[p][1];
            const float cmn = (float)pkn[p][0], cdn = (float)pkn[p][1];
            #pragma unroll
            for (int r = 0; r < 2; ++r) {
                const float m  = r ? m1 : m0;
                const float vr = acc[p][r] + fmaf(m, cdr, cmr);
                const float rr = rcp_f(1.f + __expf(-vr));
                const float vz = acc[2 + p][r] + fmaf(m, cdz, cmz);
                const float zz = rcp_f(1.f + __expf(-vz));
                const float un = fmaf(rr, acc[4 + p][r] + bhn[p], fmaf(m, cdn, cmn));
                const float ng = fmaf(-2.f, rcp_f(1.f + __expf(2.f * un)), 1.f);
                const float v  = fmaf(zz, h[p][r] - ng, ng);
                hn[p][r] = v; h[p][r] = v;
            }
        }

        if (g == 0) {
            h_lds[nxt][0][32 * w + c]      = (_Float16)hn[0][0];
            h_lds[nxt][0][32 * w + 16 + c] = (_Float16)hn[1][0];
            h_lds[nxt][1][32 * w + c]      = (_Float16)hn[0][1];
            h_lds[nxt][1][32 * w + 16 + c] = (_Float16)hn[1][1];
        }
        __syncthreads();
    }

    // epilogue: d_{SL-1} = wd . h_SL  (h_SL sits in h_lds[0], barrier passed)
    if (w >= 6) {
        f32x4 acc6 = {0.f, 0.f, 0.f, 0.f};
        const int ktb = (w == 7) ? 4 : 0;
        #pragma unroll
        for (int j = 0; j < 4; ++j) {
            half8 A = *(const half8*)&h_lds[0][c & 1][(ktb + j) * 32 + g * 8];
            acc6 = __builtin_amdgcn_mfma_f32_16x16x32_f16(A, B7f[j], acc6, 0, 0, 0);
        }
        if (lane == 0) {
            dpart[SL - 1][(w - 6) * 2]     = acc6[0];
            dpart[SL - 1][(w - 6) * 2 + 1] = acc6[1];
        }
    }
    __syncthreads();

    // post-loop: softplus over all steps, then block reduction
    float lpp0 = 0.f, lpp1 = 0.f;
    #pragma unroll 1
    for (int t = tid; t < SL; t += 512) {
        const float d0 = bd + dpart[t][0] + dpart[t][2];
        const float d1 = bd + dpart[t][1] + dpart[t][3];
        const float u0 = (x_lds[0][t + 1] > 0.5f) ? -d0 : d0;
        const float u1 = (x_lds[1][t + 1] > 0.5f) ? -d1 : d1;
        lpp0 -= fmaxf(u0, 0.f) + __logf(1.f + __expf(-fabsf(u0)));
        lpp1 -= fmaxf(u1, 0.f) + __logf(1.f + __expf(-fabsf(u1)));
    }
    #pragma unroll
    for (int s = 1; s < 64; s <<= 1) {
        lpp0 += __shfl_xor(lpp0, s);
        lpp1 += __shfl_xor(lpp1, s);
    }
    if (lane == 0) { wsum[w][0] = lpp0; wsum[w][1] = lpp1; }
    __syncthreads();
    if (tid < 2) {
        float s = 0.f;
        #pragma unroll
        for (int q = 0; q < 8; ++q) s += wsum[q][tid];
        out[row0 + tid] = s;
    }
}

extern "C" void kernel_launch(void* const* d_in, const int* in_sizes, int n_in,
                              void* d_out, int out_size, void* d_ws, size_t ws_size,
                              hipStream_t stream) {
    const float* x    = (const float*)d_in[0];
    const float* w_ih = (const float*)d_in[1];
    const float* w_hh = (const float*)d_in[2];
    const float* b_ih = (const float*)d_in[3];
    const float* b_hh = (const float*)d_in[4];
    const float* fc_w = (const float*)d_in[5];
    const float* fc_b = (const float*)d_in[6];
    gru_mfma_kernel<<<256, 512, 0, stream>>>(
        x, w_ih, w_hh, b_ih, b_hh, fc_w, fc_b, (float*)d_out);
}

// Round 7
// 1750.068 us; speedup vs baseline: 1.2237x; 1.1694x over previous
//
#include <hip/hip_runtime.h>
#include <math.h>

#define SL 1024
#define NW 256

typedef _Float16 half8 __attribute__((ext_vector_type(8)));
typedef float f32x4 __attribute__((ext_vector_type(4)));

__device__ __forceinline__ float rcp_f(float v) { return __builtin_amdgcn_rcpf(v); }

// mfma_f32_16x16x32_f16 layouts (empirically verified rounds 2/3/5):
//   A (16x32): lane row m = lane&15, k = (lane>>4)*8 + e (8 contig)
//   B (32x16): lane col n = lane&15, k = (lane>>4)*8 + e
//   D (16x16): lane col n = lane&15, row m = (lane>>4)*4 + reg
// Broadcast-A: every lane reads h row (lane&1) -> D reg r = batch row r.
// B fragments pinned in AGPRs via asm "a" constraints, consumed in place.
// gfx950 assembler rule (round-6 lesson): D and C must be in the SAME file
// (shared acc_cd bit); A/B may be AGPR freely. So zero-SrcC lives in VGPRs.
// Hazard handling: INLINEASM is not recognized as MAI by the hazard
// recognizer, so we insert an explicit 16-cycle s_nop fence between the last
// MFMA write and the first VALU read of the accumulators.
__global__ __launch_bounds__(512, 2) void gru_mfma_kernel(
    const float* __restrict__ x, const float* __restrict__ w_ih,
    const float* __restrict__ w_hh, const float* __restrict__ b_ih,
    const float* __restrict__ b_hh, const float* __restrict__ fc_w,
    const float* __restrict__ fc_b, float* __restrict__ out)
{
    const int tid  = threadIdx.x;
    const int w    = tid >> 6;     // wave 0..7
    const int lane = tid & 63;
    const int c    = lane & 15;    // unit-in-tile (B col)
    const int g    = lane >> 4;    // k-group 0..3
    const int row0 = blockIdx.x * 2;

    __shared__ float    x_lds[2][1026];                   // m values; idx0 = 0.5 (t=-1)
    __shared__ __align__(16) _Float16 h_lds[2][2][288];   // dbuf, 2 rows, stride 288
    __shared__ float    dpart[SL][8][2];                  // per-step per-wave head partials
    __shared__ float    wsum[8][2];

    for (int i = tid; i < 2 * SL; i += 512) {
        int b = i >> 10, j = i & (SL - 1);
        x_lds[b][1 + j] = (x[(size_t)(row0 + b) * SL + j] + 1.0f) * 0.5f;
    }
    if (tid < 2) x_lds[tid][0] = 0.5f;
    for (int i = tid; i < 2 * 2 * 288; i += 512)
        ((_Float16*)h_lds)[i] = (_Float16)0.0f;

    // persistent B fragments (6 unit-tiles x 8 k-tiles; f0,1=r f2,3=z f4,5=n)
    half8 Bf[6][8];
    #pragma unroll
    for (int f = 0; f < 6; ++f) {
        const int tile = (f >> 1) * 16 + 2 * w + (f & 1);
        const int u = tile * 16 + c;
        #pragma unroll
        for (int kt = 0; kt < 8; ++kt) {
            const float* p = w_hh + (size_t)u * NW + kt * 32 + g * 8;
            float4 lo = *(const float4*)p;
            float4 hi = *(const float4*)(p + 4);
            half8 hb;
            hb[0] = (_Float16)lo.x; hb[1] = (_Float16)lo.y;
            hb[2] = (_Float16)lo.z; hb[3] = (_Float16)lo.w;
            hb[4] = (_Float16)hi.x; hb[5] = (_Float16)hi.y;
            hb[6] = (_Float16)hi.z; hb[7] = (_Float16)hi.w;
            Bf[f][kt] = hb;
        }
    }

    // head fragment: wave w covers k-slice [32w, 32w+32); col 0 = wd
    half8 B7 = (half8)(_Float16)0.0f;
    if (c == 0) {
        #pragma unroll
        for (int e = 0; e < 8; ++e) {
            const int k = w * 32 + g * 8 + e;
            B7[e] = (_Float16)(fc_w[k] - fc_w[NW + k]);
        }
    }

    // VGPR zero vector for SrcC (written once, never again)
    f32x4 zacc = {0.f, 0.f, 0.f, 0.f};

    // per-lane gate constants (f32) for units u0 = 32w + c, u1 = u0 + 16
    float cmr[2], cdr[2], cmz[2], cdz[2], cmn[2], cdn[2], bhn[2];
    #pragma unroll
    for (int p = 0; p < 2; ++p) {
        const int u = 32 * w + c + (p ? 16 : 0);
        cdr[p] = w_ih[2 * u] - w_ih[2 * u + 1];
        cmr[p] = w_ih[2 * u + 1] + b_ih[u] + b_hh[u];
        cdz[p] = w_ih[2 * (NW + u)] - w_ih[2 * (NW + u) + 1];
        cmz[p] = w_ih[2 * (NW + u) + 1] + b_ih[NW + u] + b_hh[NW + u];
        cdn[p] = w_ih[2 * (2 * NW + u)] - w_ih[2 * (2 * NW + u) + 1];
        cmn[p] = w_ih[2 * (2 * NW + u) + 1] + b_ih[2 * NW + u];
        bhn[p] = b_hh[2 * NW + u];
    }
    const float bd = fc_b[0] - fc_b[1];

    float h[2][2] = {{0.f, 0.f}, {0.f, 0.f}};

    __syncthreads();

    #pragma unroll 1
    for (int t = 0; t < SL; ++t) {
        const int cur = t & 1, nxt = cur ^ 1;
        const float m0 = x_lds[0][t];
        const float m1 = x_lds[1][t];

        f32x4 acc[6];
        // kt = 0: SrcC = VGPR zero (no per-step acc init, no VALU->SrcC hazard)
        {
            half8 A = *(const half8*)&h_lds[cur][lane & 1][g * 8];
            #pragma unroll
            for (int f = 0; f < 6; ++f)
                asm("v_mfma_f32_16x16x32_f16 %0, %1, %2, %3"
                    : "=v"(acc[f]) : "v"(A), "a"(Bf[f][0]), "v"(zacc));
        }
        #pragma unroll
        for (int kt = 1; kt < 8; ++kt) {
            half8 A = *(const half8*)&h_lds[cur][lane & 1][kt * 32 + g * 8];
            #pragma unroll
            for (int f = 0; f < 6; ++f)
                asm("v_mfma_f32_16x16x32_f16 %0, %1, %2, %0"
                    : "+v"(acc[f]) : "v"(A), "a"(Bf[f][kt]));
        }
        // balanced head: one MFMA per wave on its own k-slice (uses h_t -> d_{t-1})
        f32x4 acc7;
        {
            half8 Ah = *(const half8*)&h_lds[cur][lane & 1][w * 32 + g * 8];
            asm("v_mfma_f32_16x16x32_f16 %0, %1, %2, %3"
                : "=v"(acc7) : "v"(Ah), "a"(B7), "v"(zacc));
        }
        // hazard fence: 16 cycles between last MFMA write and VALU reads
        asm volatile("s_nop 7\n\ts_nop 7"
                     : "+v"(acc[0]), "+v"(acc[1]), "+v"(acc[2]),
                       "+v"(acc[3]), "+v"(acc[4]), "+v"(acc[5]), "+v"(acc7));

        if (lane == 0 && t != 0) {
            dpart[t - 1][w][0] = acc7[0];
            dpart[t - 1][w][1] = acc7[1];
        }

        float hn[2][2];
        #pragma unroll
        for (int p = 0; p < 2; ++p) {
            #pragma unroll
            for (int r = 0; r < 2; ++r) {
                const float m  = r ? m1 : m0;
                const float vr = acc[p][r] + fmaf(m, cdr[p], cmr[p]);
                const float rr = rcp_f(1.f + __expf(-vr));
                const float vz = acc[2 + p][r] + fmaf(m, cdz[p], cmz[p]);
                const float zz = rcp_f(1.f + __expf(-vz));
                const float un = fmaf(rr, acc[4 + p][r] + bhn[p], fmaf(m, cdn[p], cmn[p]));
                const float ng = fmaf(-2.f, rcp_f(1.f + __expf(2.f * un)), 1.f);
                const float v  = fmaf(zz, h[p][r] - ng, ng);
                hn[p][r] = v; h[p][r] = v;
            }
        }

        if (g == 0) {
            h_lds[nxt][0][32 * w + c]      = (_Float16)hn[0][0];
            h_lds[nxt][0][32 * w + 16 + c] = (_Float16)hn[1][0];
            h_lds[nxt][1][32 * w + c]      = (_Float16)hn[0][1];
            h_lds[nxt][1][32 * w + 16 + c] = (_Float16)hn[1][1];
        }
        __syncthreads();
    }

    // epilogue: d_{SL-1} from h_SL (sits in h_lds[0] after final barrier)
    {
        half8 Ah = *(const half8*)&h_lds[0][lane & 1][w * 32 + g * 8];
        f32x4 accE;
        asm("v_mfma_f32_16x16x32_f16 %0, %1, %2, %3"
            : "=v"(accE) : "v"(Ah), "a"(B7), "v"(zacc));
        asm volatile("s_nop 7\n\ts_nop 7" : "+v"(accE));
        if (lane == 0) {
            dpart[SL - 1][w][0] = accE[0];
            dpart[SL - 1][w][1] = accE[1];
        }
    }
    __syncthreads();

    // post-loop: softplus over all steps, then block reduction
    float lpp0 = 0.f, lpp1 = 0.f;
    #pragma unroll 1
    for (int t = tid; t < SL; t += 512) {
        float d0 = bd, d1 = bd;
        #pragma unroll
        for (int q = 0; q < 8; ++q) { d0 += dpart[t][q][0]; d1 += dpart[t][q][1]; }
        const float u0 = (x_lds[0][t + 1] > 0.5f) ? -d0 : d0;
        const float u1 = (x_lds[1][t + 1] > 0.5f) ? -d1 : d1;
        lpp0 -= fmaxf(u0, 0.f) + __logf(1.f + __expf(-fabsf(u0)));
        lpp1 -= fmaxf(u1, 0.f) + __logf(1.f + __expf(-fabsf(u1)));
    }
    #pragma unroll
    for (int s = 1; s < 64; s <<= 1) {
        lpp0 += __shfl_xor(lpp0, s);
        lpp1 += __shfl_xor(lpp1, s);
    }
    if (lane == 0) { wsum[w][0] = lpp0; wsum[w][1] = lpp1; }
    __syncthreads();
    if (tid < 2) {
        float s = 0.f;
        #pragma unroll
        for (int q = 0; q < 8; ++q) s += wsum[q][tid];
        out[row0 + tid] = s;
    }
}

extern "C" void kernel_launch(void* const* d_in, const int* in_sizes, int n_in,
                              void* d_out, int out_size, void* d_ws, size_t ws_size,
                              hipStream_t stream) {
    const float* x    = (const float*)d_in[0];
    const float* w_ih = (const float*)d_in[1];
    const float* w_hh = (const float*)d_in[2];
    const float* b_ih = (const float*)d_in[3];
    const float* b_hh = (const float*)d_in[4];
    const float* fc_w = (const float*)d_in[5];
    const float* fc_b = (const float*)d_in[6];
    gru_mfma_kernel<<<256, 512, 0, stream>>>(
        x, w_ih, w_hh, b_ih, b_hh, fc_w, fc_b, (float*)d_out);
}

// Round 8
// 1678.424 us; speedup vs baseline: 1.2759x; 1.0427x over previous
//
#include <hip/hip_runtime.h>
#include <math.h>

#define SL 1024
#define NW 256

typedef _Float16 half8 __attribute__((ext_vector_type(8)));
typedef float f32x4 __attribute__((ext_vector_type(4)));

__device__ __forceinline__ float rcp_f(float v) { return __builtin_amdgcn_rcpf(v); }
__device__ __forceinline__ float sel4(int g, float a, float b, float c2, float d) {
    float x = (g & 1) ? b : a;
    float y = (g & 1) ? d : c2;
    return (g & 2) ? y : x;
}

// mfma_f32_16x16x32_f16 layouts (verified rounds 2-7):
//   A (16x32): lane supplies row m = lane&15, k = (lane>>4)*8 + e (8 contig)
//   B (32x16): lane supplies col n = lane&15, k = (lane>>4)*8 + e
//   D (16x16): lane holds  col n = lane&15, row m = (lane>>4)*4 + reg
// Broadcast-A: lane reads h row (lane&1) -> A row m = h[m&1] -> D reg r = batch row r (r<2).
// Partition: 4 waves x 512 regs (1 wave/SIMD). Wave w owns 12 unit-tiles
// (4 per gate: r-tiles 4w+j, z-tiles 16+4w+j, n-tiles 32+4w+j; j=0..3).
// Bf[12][8] = 384 AGPRs fits the 512 cap -> no spill (round-7 lesson).
// Lane (c,g) evals gates for ONE unit u = 64w+16g+c (acc[g], acc[4+g], acc[8+g]).
__global__ __launch_bounds__(256, 1) void gru_mfma_kernel(
    const float* __restrict__ x, const float* __restrict__ w_ih,
    const float* __restrict__ w_hh, const float* __restrict__ b_ih,
    const float* __restrict__ b_hh, const float* __restrict__ fc_w,
    const float* __restrict__ fc_b, float* __restrict__ out)
{
    const int tid  = threadIdx.x;
    const int w    = tid >> 6;     // wave 0..3
    const int lane = tid & 63;
    const int c    = lane & 15;
    const int g    = lane >> 4;    // k-group / gate-unit subgroup
    const int row0 = blockIdx.x * 2;

    __shared__ float    x_lds[2][1026];                   // m values; idx0 = 0.5 (t=-1)
    __shared__ __align__(16) _Float16 h_lds[2][2][288];   // dbuf, 2 batch rows
    __shared__ float    dpart[SL][4][2];                  // per-step per-wave head sums
    __shared__ float    wsum[4][2];

    for (int i = tid; i < 2 * SL; i += 256) {
        int b = i >> 10, j = i & (SL - 1);
        x_lds[b][1 + j] = (x[(size_t)(row0 + b) * SL + j] + 1.0f) * 0.5f;
    }
    if (tid < 2) x_lds[tid][0] = 0.5f;
    for (int i = tid; i < 2 * 2 * 288; i += 256)
        ((_Float16*)h_lds)[i] = (_Float16)0.0f;

    // persistent B fragments: f = q*4 + j -> w_hh row q*256 + (4w+j)*16 + c
    half8 Bf[12][8];
    #pragma unroll
    for (int f = 0; f < 12; ++f) {
        const int q = f >> 2, j = f & 3;
        const int urow = q * NW + (4 * w + j) * 16 + c;
        #pragma unroll
        for (int kt = 0; kt < 8; ++kt) {
            const float* p = w_hh + (size_t)urow * NW + kt * 32 + g * 8;
            float4 lo = *(const float4*)p;
            float4 hi = *(const float4*)(p + 4);
            half8 hb;
            hb[0] = (_Float16)lo.x; hb[1] = (_Float16)lo.y;
            hb[2] = (_Float16)lo.z; hb[3] = (_Float16)lo.w;
            hb[4] = (_Float16)hi.x; hb[5] = (_Float16)hi.y;
            hb[6] = (_Float16)hi.z; hb[7] = (_Float16)hi.w;
            Bf[f][kt] = hb;
        }
    }

    // gate constants for THIS lane's unit u = 64w + 16g + c
    const int u = 64 * w + 16 * g + c;
    const float cdr = w_ih[2 * u] - w_ih[2 * u + 1];
    const float cmr = w_ih[2 * u + 1] + b_ih[u] + b_hh[u];
    const float cdz = w_ih[2 * (NW + u)] - w_ih[2 * (NW + u) + 1];
    const float cmz = w_ih[2 * (NW + u) + 1] + b_ih[NW + u] + b_hh[NW + u];
    const float cdn = w_ih[2 * (2 * NW + u)] - w_ih[2 * (2 * NW + u) + 1];
    const float cmn = w_ih[2 * (2 * NW + u) + 1] + b_ih[2 * NW + u];
    const float bhn = b_hh[2 * NW + u];
    const float wd  = fc_w[u] - fc_w[NW + u];
    const float bd  = fc_b[0] - fc_b[1];

    float h0 = 0.f, h1 = 0.f;   // this lane's h[u] for batch rows 0,1

    __syncthreads();

    #pragma unroll 1
    for (int t = 0; t < SL; ++t) {
        const int cur = t & 1, nxt = cur ^ 1;
        const float m0 = x_lds[0][t];
        const float m1 = x_lds[1][t];

        f32x4 acc[12];
        #pragma unroll
        for (int f = 0; f < 12; ++f) { f32x4 z = {0.f, 0.f, 0.f, 0.f}; acc[f] = z; }

        #pragma unroll
        for (int kt = 0; kt < 8; ++kt) {
            half8 A = *(const half8*)&h_lds[cur][lane & 1][kt * 32 + g * 8];
            #pragma unroll
            for (int f = 0; f < 12; ++f)
                acc[f] = __builtin_amdgcn_mfma_f32_16x16x32_f16(A, Bf[f][kt], acc[f], 0, 0, 0);
        }

        // extract this lane's gate inputs (static acc indices; g via cndmask)
        const float ar0 = sel4(g, acc[0][0], acc[1][0], acc[2][0], acc[3][0]);
        const float ar1 = sel4(g, acc[0][1], acc[1][1], acc[2][1], acc[3][1]);
        const float az0 = sel4(g, acc[4][0], acc[5][0], acc[6][0], acc[7][0]);
        const float az1 = sel4(g, acc[4][1], acc[5][1], acc[6][1], acc[7][1]);
        const float an0 = sel4(g, acc[8][0], acc[9][0], acc[10][0], acc[11][0]);
        const float an1 = sel4(g, acc[8][1], acc[9][1], acc[10][1], acc[11][1]);

        // gates (rows 0,1)
        const float vr0 = ar0 + fmaf(m0, cdr, cmr);
        const float rr0 = rcp_f(1.f + __expf(-vr0));
        const float vz0 = az0 + fmaf(m0, cdz, cmz);
        const float zz0 = rcp_f(1.f + __expf(-vz0));
        const float un0 = fmaf(rr0, an0 + bhn, fmaf(m0, cdn, cmn));
        const float ng0 = fmaf(-2.f, rcp_f(1.f + __expf(2.f * un0)), 1.f);
        const float hn0 = fmaf(zz0, h0 - ng0, ng0);
        const float vr1 = ar1 + fmaf(m1, cdr, cmr);
        const float rr1 = rcp_f(1.f + __expf(-vr1));
        const float vz1 = az1 + fmaf(m1, cdz, cmz);
        const float zz1 = rcp_f(1.f + __expf(-vz1));
        const float un1 = fmaf(rr1, an1 + bhn, fmaf(m1, cdn, cmn));
        const float ng1 = fmaf(-2.f, rcp_f(1.f + __expf(2.f * un1)), 1.f);
        const float hn1 = fmaf(zz1, h1 - ng1, ng1);
        h0 = hn0; h1 = hn1;

        // head: d[b] += wd*hn[b]; full-wave butterfly (f32, from registers)
        float p0 = hn0 * wd;
        float p1 = hn1 * wd;
        #pragma unroll
        for (int s = 1; s < 64; s <<= 1) {
            p0 += __shfl_xor(p0, s);
            p1 += __shfl_xor(p1, s);
        }
        if (lane == 0) { dpart[t][w][0] = p0; dpart[t][w][1] = p1; }

        // h write: every lane writes its unit for both rows
        h_lds[nxt][0][u] = (_Float16)hn0;
        h_lds[nxt][1][u] = (_Float16)hn1;
        __syncthreads();
    }

    // post-loop: softplus over all steps, block reduction
    float lpp0 = 0.f, lpp1 = 0.f;
    #pragma unroll 1
    for (int t = tid; t < SL; t += 256) {
        const float d0 = bd + dpart[t][0][0] + dpart[t][1][0] + dpart[t][2][0] + dpart[t][3][0];
        const float d1 = bd + dpart[t][0][1] + dpart[t][1][1] + dpart[t][2][1] + dpart[t][3][1];
        const float u0 = (x_lds[0][t + 1] > 0.5f) ? -d0 : d0;
        const float u1 = (x_lds[1][t + 1] > 0.5f) ? -d1 : d1;
        lpp0 -= fmaxf(u0, 0.f) + __logf(1.f + __expf(-fabsf(u0)));
        lpp1 -= fmaxf(u1, 0.f) + __logf(1.f + __expf(-fabsf(u1)));
    }
    #pragma unroll
    for (int s = 1; s < 64; s <<= 1) {
        lpp0 += __shfl_xor(lpp0, s);
        lpp1 += __shfl_xor(lpp1, s);
    }
    if (lane == 0) { wsum[w][0] = lpp0; wsum[w][1] = lpp1; }
    __syncthreads();
    if (tid < 2) {
        float s = 0.f;
        #pragma unroll
        for (int q = 0; q < 4; ++q) s += wsum[q][tid];
        out[row0 + tid] = s;
    }
}

extern "C" void kernel_launch(void* const* d_in, const int* in_sizes, int n_in,
                              void* d_out, int out_size, void* d_ws, size_t ws_size,
                              hipStream_t stream) {
    const float* x    = (const float*)d_in[0];
    const float* w_ih = (const float*)d_in[1];
    const float* w_hh = (const float*)d_in[2];
    const float* b_ih = (const float*)d_in[3];
    const float* b_hh = (const float*)d_in[4];
    const float* fc_w = (const float*)d_in[5];
    const float* fc_b = (const float*)d_in[6];
    gru_mfma_kernel<<<256, 256, 0, stream>>>(
        x, w_ih, w_hh, b_ih, b_hh, fc_w, fc_b, (float*)d_out);
}

// Round 10
// 1238.668 us; speedup vs baseline: 1.7289x; 1.3550x over previous
//
#include <hip/hip_runtime.h>
#include <math.h>

#define SL 1024
#define NW 256

typedef _Float16 half8 __attribute__((ext_vector_type(8)));
typedef _Float16 half2t __attribute__((ext_vector_type(2)));
typedef float f32x4 __attribute__((ext_vector_type(4)));

__device__ __forceinline__ float rcp_f(float v) { return __builtin_amdgcn_rcpf(v); }

// mfma_f32_16x16x32_f16 (layouts verified r2-r8, builtins only):
//   A: lane row m = lane&15, k = (lane>>4)*8+e;  B: lane col n = lane&15, same k
//   D: lane col n = lane&15, row m = (lane>>4)*4 + reg
// Broadcast-A (lane reads h row lane&1): D row m = gh[m&1] -> on EVERY lane,
// acc regs 0,1 = batch rows 0,1.
// Partition: 512 threads, 8 waves, 2 waves/SIMD (TLP hides the AGPR->VGPR
// B-shuttle under the other wave's MFMA pipe time -- r8's stall source).
// Wave w owns 6 tiles: gate q tile (2w+j), j=0,1 -> units 32w..32w+31 for all
// 3 gates (gate eval stays wave-local). Budget/wave <= 256: Bf 192 + acc 24
// (AGPR) + ~38 arch. Gate consts f16-packed. A loaded per-kt (no prefetch).
__global__ __launch_bounds__(512, 2) void gru_mfma_kernel(
    const float* __restrict__ x, const float* __restrict__ w_ih,
    const float* __restrict__ w_hh, const float* __restrict__ b_ih,
    const float* __restrict__ b_hh, const float* __restrict__ fc_w,
    const float* __restrict__ fc_b, float* __restrict__ out)
{
    const int tid  = threadIdx.x;
    const int w    = tid >> 6;     // wave 0..7
    const int lane = tid & 63;
    const int c    = lane & 15;
    const int g    = lane >> 4;    // k-group for A/B fragments
    const int gl   = g & 1;        // tile parity for gate eval (g>=2 duplicates)
    const int row0 = blockIdx.x * 2;

    __shared__ float    x_lds[2][1026];                   // m values; idx0 = 0.5 (t=-1)
    __shared__ __align__(16) _Float16 h_lds[2][2][288];   // dbuf, 2 batch rows
    __shared__ float    dpart[SL][8][2];                  // per-step per-wave head sums
    __shared__ float    wsum[8][2];

    for (int i = tid; i < 2 * SL; i += 512) {
        int b = i >> 10, j = i & (SL - 1);
        x_lds[b][1 + j] = (x[(size_t)(row0 + b) * SL + j] + 1.0f) * 0.5f;
    }
    if (tid < 2) x_lds[tid][0] = 0.5f;
    for (int i = tid; i < 2 * 2 * 288; i += 512)
        ((_Float16*)h_lds)[i] = (_Float16)0.0f;

    // persistent B fragments: f = q*2 + j -> w_hh row q*256 + (2w+j)*16 + c
    half8 Bf[6][8];
    #pragma unroll
    for (int f = 0; f < 6; ++f) {
        const int q = f >> 1, j = f & 1;
        const int urow = q * NW + (2 * w + j) * 16 + c;
        #pragma unroll
        for (int kt = 0; kt < 8; ++kt) {
            const float* p = w_hh + (size_t)urow * NW + kt * 32 + g * 8;
            float4 lo = *(const float4*)p;
            float4 hi = *(const float4*)(p + 4);
            half8 hb;
            hb[0] = (_Float16)lo.x; hb[1] = (_Float16)lo.y;
            hb[2] = (_Float16)lo.z; hb[3] = (_Float16)lo.w;
            hb[4] = (_Float16)hi.x; hb[5] = (_Float16)hi.y;
            hb[6] = (_Float16)hi.z; hb[7] = (_Float16)hi.w;
            Bf[f][kt] = hb;
        }
    }

    // gate constants for THIS lane's unit u = 32w + 16gl + c (f16-packed pairs)
    const int u = 32 * w + 16 * gl + c;
    half2t pkr, pkz, pkn;
    {
        float w0, w1;
        w0 = w_ih[2 * u]; w1 = w_ih[2 * u + 1];
        pkr[0] = (_Float16)(w1 + b_ih[u] + b_hh[u]);
        pkr[1] = (_Float16)(w0 - w1);
        w0 = w_ih[2 * (NW + u)]; w1 = w_ih[2 * (NW + u) + 1];
        pkz[0] = (_Float16)(w1 + b_ih[NW + u] + b_hh[NW + u]);
        pkz[1] = (_Float16)(w0 - w1);
        w0 = w_ih[2 * (2 * NW + u)]; w1 = w_ih[2 * (2 * NW + u) + 1];
        pkn[0] = (_Float16)(w1 + b_ih[2 * NW + u]);
        pkn[1] = (_Float16)(w0 - w1);
    }
    const float bhn = b_hh[2 * NW + u];
    const float wd  = fc_w[u] - fc_w[NW + u];
    const float bd  = fc_b[0] - fc_b[1];

    float h0 = 0.f, h1 = 0.f;

    __syncthreads();

    #pragma unroll 1
    for (int t = 0; t < SL; ++t) {
        const int cur = t & 1, nxt = cur ^ 1;

        f32x4 acc[6];
        #pragma unroll
        for (int f = 0; f < 6; ++f) { f32x4 z = {0.f, 0.f, 0.f, 0.f}; acc[f] = z; }

        #pragma unroll
        for (int kt = 0; kt < 8; ++kt) {
            half8 A = *(const half8*)&h_lds[cur][lane & 1][kt * 32 + g * 8];
            #pragma unroll
            for (int f = 0; f < 6; ++f)
                acc[f] = __builtin_amdgcn_mfma_f32_16x16x32_f16(A, Bf[f][kt], acc[f], 0, 0, 0);
        }

        const float m0 = x_lds[0][t];
        const float m1 = x_lds[1][t];

        // this lane's gate inputs: tile parity gl via cndmask, batch row = reg
        const float ar0 = gl ? acc[1][0] : acc[0][0];
        const float ar1 = gl ? acc[1][1] : acc[0][1];
        const float az0 = gl ? acc[3][0] : acc[2][0];
        const float az1 = gl ? acc[3][1] : acc[2][1];
        const float an0 = gl ? acc[5][0] : acc[4][0];
        const float an1 = gl ? acc[5][1] : acc[4][1];

        const float cmr = (float)pkr[0], cdr = (float)pkr[1];
        const float cmz = (float)pkz[0], cdz = (float)pkz[1];
        const float cmn = (float)pkn[0], cdn = (float)pkn[1];

        const float vr0 = ar0 + fmaf(m0, cdr, cmr);
        const float rr0 = rcp_f(1.f + __expf(-vr0));
        const float vz0 = az0 + fmaf(m0, cdz, cmz);
        const float zz0 = rcp_f(1.f + __expf(-vz0));
        const float un0 = fmaf(rr0, an0 + bhn, fmaf(m0, cdn, cmn));
        const float ng0 = fmaf(-2.f, rcp_f(1.f + __expf(2.f * un0)), 1.f);
        const float hn0 = fmaf(zz0, h0 - ng0, ng0);
        const float vr1 = ar1 + fmaf(m1, cdr, cmr);
        const float rr1 = rcp_f(1.f + __expf(-vr1));
        const float vz1 = az1 + fmaf(m1, cdz, cmz);
        const float zz1 = rcp_f(1.f + __expf(-vz1));
        const float un1 = fmaf(rr1, an1 + bhn, fmaf(m1, cdn, cmn));
        const float ng1 = fmaf(-2.f, rcp_f(1.f + __expf(2.f * un1)), 1.f);
        const float hn1 = fmaf(zz1, h1 - ng1, ng1);
        h0 = hn0; h1 = hn1;

        if (g < 2) {
            h_lds[nxt][0][u] = (_Float16)hn0;
            h_lds[nxt][1][u] = (_Float16)hn1;
        }

        // head: zero duplicate lanes (g>=2), butterfly over full wave
        float p0 = (g < 2) ? hn0 * wd : 0.f;
        float p1 = (g < 2) ? hn1 * wd : 0.f;
        #pragma unroll
        for (int s = 1; s < 64; s <<= 1) {
            p0 += __shfl_xor(p0, s);
            p1 += __shfl_xor(p1, s);
        }
        if (lane == 0) { dpart[t][w][0] = p0; dpart[t][w][1] = p1; }

        __syncthreads();
    }

    // post-loop: softplus over all steps, block reduction
    float lpp0 = 0.f, lpp1 = 0.f;
    #pragma unroll 1
    for (int t = tid; t < SL; t += 512) {
        float d0 = bd, d1 = bd;
        #pragma unroll
        for (int q = 0; q < 8; ++q) { d0 += dpart[t][q][0]; d1 += dpart[t][q][1]; }
        const float u0 = (x_lds[0][t + 1] > 0.5f) ? -d0 : d0;
        const float u1 = (x_lds[1][t + 1] > 0.5f) ? -d1 : d1;
        lpp0 -= fmaxf(u0, 0.f) + __logf(1.f + __expf(-fabsf(u0)));
        lpp1 -= fmaxf(u1, 0.f) + __logf(1.f + __expf(-fabsf(u1)));
    }
    #pragma unroll
    for (int s = 1; s < 64; s <<= 1) {
        lpp0 += __shfl_xor(lpp0, s);
        lpp1 += __shfl_xor(lpp1, s);
    }
    if (lane == 0) { wsum[w][0] = lpp0; wsum[w][1] = lpp1; }
    __syncthreads();
    if (tid < 2) {
        float s = 0.f;
        #pragma unroll
        for (int q = 0; q < 8; ++q) s += wsum[q][tid];
        out[row0 + tid] = s;
    }
}

extern "C" void kernel_launch(void* const* d_in, const int* in_sizes, int n_in,
                              void* d_out, int out_size, void* d_ws, size_t ws_size,
                              hipStream_t stream) {
    const float* x    = (const float*)d_in[0];
    const float* w_ih = (const float*)d_in[1];
    const float* w_hh = (const float*)d_in[2];
    const float* b_ih = (const float*)d_in[3];
    const float* b_hh = (const float*)d_in[4];
    const float* fc_w = (const float*)d_in[5];
    const float* fc_b = (const float*)d_in[6];
    gru_mfma_kernel<<<256, 512, 0, stream>>>(
        x, w_ih, w_hh, b_ih, b_hh, fc_w, fc_b, (float*)d_out);
}